// Round 11
// baseline (42.791 us; speedup 1.0000x reference)
//
#include <hip/hip_runtime.h>

// Problem constants: B=4, N=M=4096, P=2048.
#define BB 4
#define NN 4096
#define PP 2048

#define NPAIR 2048     // candidate pairs per block (all 4096 candidates)
#define QPT 16         // queries per wave (wave-uniform)
#define QPB 64         // queries per block = 4 waves * QPT

typedef float f2 __attribute__((ext_vector_type(2)));

#if __has_builtin(__builtin_elementwise_fma)
#define PKFMA(a, b, c) __builtin_elementwise_fma((a), (b), (c))
#else
#define PKFMA(a, b, c) ((a) * (b) + (c))   // -ffp-contract fuses to pk_fma
#endif

// Packed-fp32 NN: candidates staged ONCE per block into pair-SoA LDS
// (scx=(x0,x1,y0,y1), scz=(z0,z1)); |c|^2 recomputed packed per wave.
// Inner: per query per candidate-pair = 3 v_pk_fma_f32 + 1 v_min3_f32
// (2.0 wave-instr per pair, was 3.5 scalar). Barrier-free main loop.
//
// Block map (grid = 960, 256 threads = 4 waves):
//    0..255 : A pred->full    (b=blk>>6, ch=blk&63)
//  256..511 : B full->pred
//  512..639 : C partial->pred (b=u>>5, ch=u&31)
//  640..895 : D pred->refl(pred)  (symmetric matrix -> one direction x2)
//  896..959 : E normal consistency
// res slot = blk*4+wv (NN), 3584+(blk-896) (NC); final_kernel reduces.

__global__ __launch_bounds__(256, 3) void nn_kernel(
    const float* __restrict__ pred, const float* __restrict__ full,
    const float* __restrict__ partial, const float* __restrict__ plane_n,
    const float* __restrict__ plane_off,
    const float* __restrict__ pn, const float* __restrict__ gn,
    float* __restrict__ res)
{
    int blk = blockIdx.x;
    int tid = threadIdx.x;
    __shared__ float4 scx[NPAIR];   // 32 KB
    __shared__ float2 scz[NPAIR];   // 16 KB

    if (blk >= 896) {
        // ---- NC: normal consistency ----
        __shared__ float sred[4];
        int i = (blk - 896) * 256 + tid;
        const float* p = pn + (size_t)i * 3;
        const float* g = gn + (size_t)i * 3;
        float px = p[0], py = p[1], pz = p[2];
        float gx = g[0], gy = g[1], gz = g[2];
        float num = fmaf(px, gx, fmaf(py, gy, pz * gz));
        float den = sqrtf(fmaf(px, px, fmaf(py, py, pz * pz))) *
                    sqrtf(fmaf(gx, gx, fmaf(gy, gy, gz * gz)));
        float v = 1.f - fabsf(num / fmaxf(den, 1e-8f));
        for (int o = 1; o < 64; o <<= 1) v += __shfl_xor(v, o);
        if ((tid & 63) == 0) sred[tid >> 6] = v;
        __syncthreads();
        if (tid == 0) res[3584 + (blk - 896)] = sred[0] + sred[1] + sred[2] + sred[3];
        return;
    }

    // ---- decode ----
    const float* cand; const float* qptr; bool reflect = false; int b;
    if (blk < 256) {                       // A: pred -> full
        b = blk >> 6; int ch = blk & 63;
        cand = full + (size_t)b * NN * 3;
        qptr = pred + ((size_t)b * NN + ch * QPB) * 3;
    } else if (blk < 512) {                // B: full -> pred
        int u = blk - 256; b = u >> 6; int ch = u & 63;
        cand = pred + (size_t)b * NN * 3;
        qptr = full + ((size_t)b * NN + ch * QPB) * 3;
    } else if (blk < 640) {                // C: partial -> pred
        int u = blk - 512; b = u >> 5; int ch = u & 31;
        cand = pred + (size_t)b * NN * 3;
        qptr = partial + ((size_t)b * PP + ch * QPB) * 3;
    } else {                               // D: pred -> refl(pred)
        int u = blk - 640; b = u >> 6; int ch = u & 63;
        cand = pred + (size_t)b * NN * 3;
        qptr = pred + ((size_t)b * NN + ch * QPB) * 3;
        reflect = true;
    }

    float nx = 0.f, ny = 0.f, nz = 0.f, noff = 0.f;
    if (reflect) {
        nx = plane_n[b * 3]; ny = plane_n[b * 3 + 1]; nz = plane_n[b * 3 + 2];
        noff = plane_off[b];
    }

    // ---- stage 2048 pairs (4096 cands), reflect inline, pair-SoA ----
#pragma unroll
    for (int r = 0; r < NPAIR / 256; ++r) {
        int p = r * 256 + tid;
        const float* cp = cand + (size_t)p * 6;
        float2 v0 = *(const float2*)(cp);       // x0,y0
        float2 v1 = *(const float2*)(cp + 2);   // z0,x1
        float2 v2 = *(const float2*)(cp + 4);   // y1,z1
        float x0 = v0.x, y0 = v0.y, z0 = v1.x;
        float x1 = v1.y, y1 = v2.x, z1 = v2.y;
        if (reflect) {
            float s0 = fmaf(x0, nx, fmaf(y0, ny, fmaf(z0, nz, noff)));
            float t0 = 2.0f * s0;
            x0 -= t0 * nx; y0 -= t0 * ny; z0 -= t0 * nz;
            float s1 = fmaf(x1, nx, fmaf(y1, ny, fmaf(z1, nz, noff)));
            float t1 = 2.0f * s1;
            x1 -= t1 * nx; y1 -= t1 * ny; z1 -= t1 * nz;
        }
        scx[p] = make_float4(x0, x1, y0, y1);
        scz[p] = make_float2(z0, z1);
    }
    __syncthreads();

    // ---- wave-uniform queries: (-2q) packed into both f2 halves ----
    int lane = tid & 63;
    int wv = __builtin_amdgcn_readfirstlane(tid >> 6);
    const float* qp = qptr + (size_t)wv * QPT * 3;
    f2 qx2[QPT], qy2[QPT], qz2[QPT];
    float md[QPT];
#pragma unroll
    for (int j = 0; j < QPT; ++j) {
        float qx = qp[j * 3], qy = qp[j * 3 + 1], qz = qp[j * 3 + 2];
        qx2[j] = (f2){-2.f * qx, -2.f * qx};
        qy2[j] = (f2){-2.f * qy, -2.f * qy};
        qz2[j] = (f2){-2.f * qz, -2.f * qz};
        md[j] = 3.4e38f;
    }

    // ---- barrier-free main loop: 1 pair/lane/iter, 128 cands/wave/iter ----
#pragma unroll 8
    for (int k = 0; k < NPAIR / 64; ++k) {
        float4 cxy = scx[k * 64 + lane];
        float2 czz = scz[k * 64 + lane];
        f2 cx2 = (f2){cxy.x, cxy.y};
        f2 cy2 = (f2){cxy.z, cxy.w};
        f2 cz2 = (f2){czz.x, czz.y};
        f2 cw2 = PKFMA(cz2, cz2, PKFMA(cy2, cy2, cx2 * cx2));   // |c|^2 packed
#pragma unroll
        for (int j = 0; j < QPT; ++j) {
            f2 t = PKFMA(cx2, qx2[j], PKFMA(cy2, qy2[j], PKFMA(cz2, qz2[j], cw2)));
            md[j] = fminf(md[j], fminf(t.x, t.y));   // v_min3_f32
        }
    }

    // ---- cross-lane min; lane0 adds |q|^2, sqrt, sums 16 queries ----
#pragma unroll
    for (int j = 0; j < QPT; ++j) {
        md[j] = fminf(md[j], __shfl_xor(md[j], 1));
        md[j] = fminf(md[j], __shfl_xor(md[j], 2));
        md[j] = fminf(md[j], __shfl_xor(md[j], 4));
        md[j] = fminf(md[j], __shfl_xor(md[j], 8));
        md[j] = fminf(md[j], __shfl_xor(md[j], 16));
        md[j] = fminf(md[j], __shfl_xor(md[j], 32));
    }
    if (lane == 0) {
        float s = 0.f;
#pragma unroll
        for (int j = 0; j < QPT; ++j) {
            float qx = qp[j * 3], qy = qp[j * 3 + 1], qz = qp[j * 3 + 2];
            float q2 = fmaf(qx, qx, fmaf(qy, qy, qz * qz));
            s += sqrtf(fmaxf(q2 + md[j], 0.f));
        }
        res[blk * 4 + wv] = s;
    }
}

__global__ __launch_bounds__(256) void final_kernel(
    const float* __restrict__ res,
    const float* __restrict__ confs,
    const float* __restrict__ diff,
    float* __restrict__ out)
{
    __shared__ float seg[8];
    int tid = threadIdx.x;
    if (tid < 8) seg[tid] = 0.f;
    __syncthreads();
    for (int i = tid; i < 3648; i += 256) {
        float v = res[i];
        int sgi;
        if (i < 1024) sgi = 0;
        else if (i < 2048) sgi = 1;
        else if (i < 2560) sgi = 2;
        else if (i < 3584) sgi = 3 + ((i - 2560) >> 8);
        else sgi = 7;
        atomicAdd(&seg[sgi], v);
    }
    __syncthreads();
    if (tid == 0) {
        const float BN = (float)(BB * NN);
        const float BP = (float)(BB * PP);
        float cd  = seg[0] / BN + seg[1] / BN;
        float fid = seg[2] / BP;
        float nc  = seg[7] / BN;
        float sym = 0.f;
#pragma unroll
        for (int b = 0; b < BB; ++b) {
            float conf = confs[b];
            if (conf >= 0.25f) {
                // symmetric distance matrix -> both chamfer directions equal
                float cdl1 = 2.0f * seg[3 + b] / (float)NN;
                sym += conf * cdl1 * 0.5f;
            }
        }
        sym *= (1.0f / BB);
        out[0] = 1.0f * cd + 0.5f * fid + 0.1f * nc + 0.1f * sym + diff[0];
    }
}

extern "C" void kernel_launch(void* const* d_in, const int* in_sizes, int n_in,
                              void* d_out, int out_size, void* d_ws, size_t ws_size,
                              hipStream_t stream) {
    const float* pred      = (const float*)d_in[0];
    const float* full      = (const float*)d_in[1];
    const float* partial   = (const float*)d_in[2];
    // d_in[3]=mu, d_in[4]=logvar: KL term has coefficient 0 -> unused
    const float* pred_n    = (const float*)d_in[5];
    const float* gt_n      = (const float*)d_in[6];
    const float* plane_n   = (const float*)d_in[7];
    const float* plane_off = (const float*)d_in[8];
    const float* confs     = (const float*)d_in[9];
    const float* diff      = (const float*)d_in[10];
    float* res = (float*)d_ws;

    nn_kernel<<<960, 256, 0, stream>>>(pred, full, partial, plane_n,
                                       plane_off, pred_n, gt_n, res);
    final_kernel<<<1, 256, 0, stream>>>(res, confs, diff, (float*)d_out);
}